// Round 1
// baseline (368.243 us; speedup 1.0000x reference)
//
#include <hip/hip_runtime.h>

// Problem constants (match setup_inputs): B=2, Y=X=200, N=40000, C=128, H=4, P=8, D=32
#define BQ 2
#define YY 200
#define XX 200
#define NQ 40000
#define CC 128
#define MTOT 80000   // BQ*NQ
#define NCOL 224     // 128 (value) + 64 (off) + 32 (attn logits)

typedef __attribute__((ext_vector_type(8))) short short8;
typedef __attribute__((ext_vector_type(4))) float f32x4;

static __device__ __forceinline__ unsigned short f2bf(float f) {
    union { float f; unsigned int u; } v; v.f = f;
    unsigned int r = v.u + 0x7FFF + ((v.u >> 16) & 1);  // round-to-nearest-even
    return (unsigned short)(r >> 16);
}
static __device__ __forceinline__ float bf2f(unsigned short s) {
    union { unsigned int u; float f; } v; v.u = ((unsigned int)s) << 16;
    return v.f;
}

// ---- prep: WcatT[224][128] bf16 = [Wv | Woff | Wattn] transposed ----
__global__ void prep_wcat(const float* __restrict__ Wv, const float* __restrict__ Woff,
                          const float* __restrict__ Wattn, unsigned short* __restrict__ WcatT) {
    int idx = blockIdx.x * 256 + threadIdx.x;       // 224*128 = 28672 = 112 blocks
    if (idx >= NCOL * CC) return;
    int c = idx >> 7, k = idx & 127;
    float w = (c < 128) ? Wv[k * 128 + c]
            : (c < 192) ? Woff[k * 64 + (c - 128)]
                        : Wattn[k * 32 + (c - 192)];
    WcatT[c * 128 + k] = f2bf(w);
}

// ---- prep: W12T[128][128] bf16 = (Wout1@Wout2)^T ; b12 = bout1@Wout2 + bout2 ----
__global__ void prep_w12(const float* __restrict__ Wout1, const float* __restrict__ Wout2,
                         const float* __restrict__ bout1, const float* __restrict__ bout2,
                         unsigned short* __restrict__ W12T, float* __restrict__ b12) {
    int idx = blockIdx.x * 256 + threadIdx.x;       // 16384 = 64 blocks
    int c = idx >> 7, k = idx & 127;
    float s = 0.f;
    for (int j = 0; j < 128; ++j) s += Wout1[k * 128 + j] * Wout2[j * 128 + c];
    W12T[c * 128 + k] = f2bf(s);
    if (k == 0) {
        float t = bout2[c];
        for (int j = 0; j < 128; ++j) t += bout1[j] * Wout2[j * 128 + c];
        b12[c] = t;
    }
}

// ---- G1: fused projection GEMM. q = query+qpos (bf16), [value|off|logits] = q @ Wcat ----
// 64 rows/block, 4 waves, each wave 16 rows x 224 cols (14 MFMA tiles), K=128 (4 ksteps)
__global__ __launch_bounds__(256) void g1_kernel(
    const float* __restrict__ query, const float* __restrict__ qpos,
    const unsigned short* __restrict__ WcatT,
    const float* __restrict__ bv, const float* __restrict__ boff, const float* __restrict__ battn,
    unsigned short* __restrict__ value_bf, float* __restrict__ off_out, float* __restrict__ logits_out)
{
    __shared__ short Alds[64 * 128];   // bf16, XOR-swizzled rows
    const int tid = threadIdx.x;
    const int rowBase = blockIdx.x * 64;

    // stage A: q = query + qpos -> bf16 LDS
    {
        int r = tid >> 2;                 // 0..63
        int c0 = (tid & 3) * 32;          // 0,32,64,96
        const float4* qa = (const float4*)(query + (size_t)(rowBase + r) * CC + c0);
        const float4* qb = (const float4*)(qpos  + (size_t)(rowBase + r) * CC + c0);
#pragma unroll
        for (int j = 0; j < 4; ++j) {
            float4 x0 = qa[2 * j], x1 = qa[2 * j + 1];
            float4 y0 = qb[2 * j], y1 = qb[2 * j + 1];
            short8 w;
            w[0] = (short)f2bf(x0.x + y0.x); w[1] = (short)f2bf(x0.y + y0.y);
            w[2] = (short)f2bf(x0.z + y0.z); w[3] = (short)f2bf(x0.w + y0.w);
            w[4] = (short)f2bf(x1.x + y1.x); w[5] = (short)f2bf(x1.y + y1.y);
            w[6] = (short)f2bf(x1.z + y1.z); w[7] = (short)f2bf(x1.w + y1.w);
            int byte = (r * 256 + (c0 + j * 8) * 2) ^ ((r & 7) << 4);
            *(short8*)((char*)Alds + byte) = w;
        }
    }
    __syncthreads();

    const int wave = tid >> 6, lane = tid & 63;
    const int arow = lane & 15, kq = lane >> 4;
    const int wrow = wave * 16;

    f32x4 acc[14];
#pragma unroll
    for (int t = 0; t < 14; ++t) acc[t] = (f32x4){0.f, 0.f, 0.f, 0.f};

#pragma unroll
    for (int ks = 0; ks < 4; ++ks) {
        int r = wrow + arow;
        int byte = (r * 256 + (ks * 32 + kq * 8) * 2) ^ ((r & 7) << 4);
        short8 a = *(const short8*)((const char*)Alds + byte);
#pragma unroll
        for (int t = 0; t < 14; ++t) {
            int col = t * 16 + arow;
            short8 b = *(const short8*)(WcatT + (size_t)col * 128 + ks * 32 + kq * 8);
            acc[t] = __builtin_amdgcn_mfma_f32_16x16x32_bf16(a, b, acc[t], 0, 0, 0);
        }
    }

    // epilogue: cols 0..127 -> value (bf16, +bv); 128..191 -> off (f32, +boff); 192..223 -> logits (f32, +battn)
#pragma unroll
    for (int t = 0; t < 14; ++t) {
        int col = t * 16 + (lane & 15);
#pragma unroll
        for (int rr = 0; rr < 4; ++rr) {
            int row = wrow + kq * 4 + rr;
            size_t grow = (size_t)(rowBase + row);
            float v = acc[t][rr];
            if (col < 128) {
                value_bf[grow * 128 + col] = f2bf(v + bv[col]);
            } else if (col < 192) {
                off_out[grow * 64 + (col - 128)] = v + boff[col - 128];
            } else {
                logits_out[grow * 32 + (col - 192)] = v + battn[col - 192];
            }
        }
    }
}

// ---- sampling: softmax(P=8 per head) + bilinear gather + weighted sum over P ----
// 8 queries/block, 32 lanes per query (lane = channel d within head)
__global__ __launch_bounds__(256) void sample_kernel(
    const unsigned short* __restrict__ value_bf, const float* __restrict__ off_in,
    const float* __restrict__ logits, unsigned short* __restrict__ sampled)
{
    const int lane = threadIdx.x & 31;
    const int r = blockIdx.x * 8 + (threadIdx.x >> 5);   // query row, 0..79999
    const int b = r / NQ;
    const int n = r - b * NQ;
    const int yq = n / XX, xq = n - yq * XX;

    // softmax over P within each head; lane <-> (h = lane>>3, p = lane&7)
    float lg = logits[(size_t)r * 32 + lane];
    float m = lg;
    m = fmaxf(m, __shfl_xor(m, 1));
    m = fmaxf(m, __shfl_xor(m, 2));
    m = fmaxf(m, __shfl_xor(m, 4));
    float e = __expf(lg - m);
    float s = e;
    s += __shfl_xor(s, 1);
    s += __shfl_xor(s, 2);
    s += __shfl_xor(s, 4);
    float aw = e / s;

    // offsets: faithful to reference quirk: gx (x-coord) = yq + off0, gy (y-coord) = xq + off1
    float2 o = ((const float2*)(off_in + (size_t)r * 64))[lane];
    float gx = (float)yq + o.x;
    float gy = (float)xq + o.y;

    const unsigned short* vb = value_bf + (size_t)b * NQ * 128;

#pragma unroll
    for (int h = 0; h < 4; ++h) {
        float acc = 0.f;
#pragma unroll
        for (int p = 0; p < 8; ++p) {
            const int hp = h * 8 + p;
            float bx = __shfl(gx, hp, 32);
            float by = __shfl(gy, hp, 32);
            float w  = __shfl(aw, hp, 32);
            float fx = floorf(bx), fy = floorf(by);
            int x0 = (int)fx, y0 = (int)fy;
            float wx1 = bx - fx, wy1 = by - fy;
            float wx0 = 1.f - wx1, wy0 = 1.f - wy1;

            float v00 = 0.f, v01 = 0.f, v10 = 0.f, v11 = 0.f;
            if ((unsigned)y0 < YY && (unsigned)x0 < XX)
                v00 = bf2f(vb[((size_t)y0 * XX + x0) * 128 + h * 32 + lane]);
            if ((unsigned)y0 < YY && (unsigned)(x0 + 1) < XX)
                v01 = bf2f(vb[((size_t)y0 * XX + x0 + 1) * 128 + h * 32 + lane]);
            if ((unsigned)(y0 + 1) < YY && (unsigned)x0 < XX)
                v10 = bf2f(vb[((size_t)(y0 + 1) * XX + x0) * 128 + h * 32 + lane]);
            if ((unsigned)(y0 + 1) < YY && (unsigned)(x0 + 1) < XX)
                v11 = bf2f(vb[((size_t)(y0 + 1) * XX + x0 + 1) * 128 + h * 32 + lane]);

            acc += w * (wy0 * (wx0 * v00 + wx1 * v01) + wy1 * (wx0 * v10 + wx1 * v11));
        }
        sampled[(size_t)r * 128 + h * 32 + lane] = f2bf(acc);
    }
}

// ---- G2: out = sampled @ W12 + b12 + query (residual). M=80000, N=128, K=128 ----
__global__ __launch_bounds__(256) void g2_kernel(
    const unsigned short* __restrict__ sampled, const unsigned short* __restrict__ W12T,
    const float* __restrict__ b12, const float* __restrict__ query, float* __restrict__ out)
{
    __shared__ short Alds[64 * 128];
    const int tid = threadIdx.x;
    const int rowBase = blockIdx.x * 64;

    {
        int r = tid >> 2;
        int c0 = (tid & 3) * 32;
        const short8* sp = (const short8*)(sampled + (size_t)(rowBase + r) * 128 + c0);
#pragma unroll
        for (int j = 0; j < 4; ++j) {
            short8 w = sp[j];
            int byte = (r * 256 + (c0 + j * 8) * 2) ^ ((r & 7) << 4);
            *(short8*)((char*)Alds + byte) = w;
        }
    }
    __syncthreads();

    const int wave = tid >> 6, lane = tid & 63;
    const int arow = lane & 15, kq = lane >> 4;
    const int wrow = wave * 16;

    f32x4 acc[8];
#pragma unroll
    for (int t = 0; t < 8; ++t) acc[t] = (f32x4){0.f, 0.f, 0.f, 0.f};

#pragma unroll
    for (int ks = 0; ks < 4; ++ks) {
        int r = wrow + arow;
        int byte = (r * 256 + (ks * 32 + kq * 8) * 2) ^ ((r & 7) << 4);
        short8 a = *(const short8*)((const char*)Alds + byte);
#pragma unroll
        for (int t = 0; t < 8; ++t) {
            int col = t * 16 + arow;
            short8 b = *(const short8*)(W12T + (size_t)col * 128 + ks * 32 + kq * 8);
            acc[t] = __builtin_amdgcn_mfma_f32_16x16x32_bf16(a, b, acc[t], 0, 0, 0);
        }
    }

#pragma unroll
    for (int t = 0; t < 8; ++t) {
        int col = t * 16 + (lane & 15);
#pragma unroll
        for (int rr = 0; rr < 4; ++rr) {
            int row = wrow + kq * 4 + rr;
            size_t grow = (size_t)(rowBase + row);
            out[grow * 128 + col] = acc[t][rr] + b12[col] + query[grow * 128 + col];
        }
    }
}

extern "C" void kernel_launch(void* const* d_in, const int* in_sizes, int n_in,
                              void* d_out, int out_size, void* d_ws, size_t ws_size,
                              hipStream_t stream) {
    const float* query = (const float*)d_in[0];
    const float* qpos  = (const float*)d_in[1];
    const float* Wv    = (const float*)d_in[2];
    const float* bv    = (const float*)d_in[3];
    const float* Woff  = (const float*)d_in[4];
    const float* boff  = (const float*)d_in[5];
    const float* Wattn = (const float*)d_in[6];
    const float* battn = (const float*)d_in[7];
    const float* Wout1 = (const float*)d_in[8];
    const float* bout1 = (const float*)d_in[9];
    const float* Wout2 = (const float*)d_in[10];
    const float* bout2 = (const float*)d_in[11];
    float* out = (float*)d_out;

    char* ws = (char*)d_ws;
    unsigned short* value_bf = (unsigned short*)(ws);                 // 80000*128*2 = 20,480,000
    float*          off_buf  = (float*)(ws + 20480000);               // 80000*64*4  = 20,480,000
    float*          logits   = (float*)(ws + 40960000);               // 80000*32*4  = 10,240,000
    unsigned short* sampled  = (unsigned short*)(ws + 51200000);      // 80000*128*2 = 20,480,000
    unsigned short* WcatT    = (unsigned short*)(ws + 71680000);      // 224*128*2   = 57,344
    unsigned short* W12T     = (unsigned short*)(ws + 71680000 + 57344);  // 128*128*2 = 32,768
    float*          b12      = (float*)(ws + 71680000 + 57344 + 32768);   // 512
    // total ~71.8 MB

    prep_wcat<<<112, 256, 0, stream>>>(Wv, Woff, Wattn, WcatT);
    prep_w12<<<64, 256, 0, stream>>>(Wout1, Wout2, bout1, bout2, W12T, b12);
    g1_kernel<<<MTOT / 64, 256, 0, stream>>>(query, qpos, WcatT, bv, boff, battn,
                                             value_bf, off_buf, logits);
    sample_kernel<<<MTOT / 8, 256, 0, stream>>>(value_bf, off_buf, logits, sampled);
    g2_kernel<<<MTOT / 64, 256, 0, stream>>>(sampled, W12T, b12, query, out);
}

// Round 2
// 138.203 us; speedup vs baseline: 2.6645x; 2.6645x over previous
//
#include <hip/hip_runtime.h>

// Problem constants (match setup_inputs): B=2, Y=X=200, N=40000, C=128, H=4, P=8, D=32
#define BQ 2
#define YY 200
#define XX 200
#define NQ 40000
#define CC 128
#define MTOT 80000   // BQ*NQ
#define NCOL 224     // 128 (value) + 64 (off) + 32 (attn logits)

typedef __attribute__((ext_vector_type(8))) short short8;
typedef __attribute__((ext_vector_type(4))) float f32x4;

static __device__ __forceinline__ unsigned short f2bf(float f) {
    union { float f; unsigned int u; } v; v.f = f;
    unsigned int r = v.u + 0x7FFF + ((v.u >> 16) & 1);  // round-to-nearest-even
    return (unsigned short)(r >> 16);
}

// ---- prep: WcatT[224][128] bf16 = [Wv | Woff | Wattn] transposed ----
__global__ void prep_wcat(const float* __restrict__ Wv, const float* __restrict__ Woff,
                          const float* __restrict__ Wattn, unsigned short* __restrict__ WcatT) {
    int idx = blockIdx.x * 256 + threadIdx.x;       // 224*128 = 28672 = 112 blocks
    if (idx >= NCOL * CC) return;
    int c = idx >> 7, k = idx & 127;
    float w = (c < 128) ? Wv[k * 128 + c]
            : (c < 192) ? Woff[k * 64 + (c - 128)]
                        : Wattn[k * 32 + (c - 192)];
    WcatT[c * 128 + k] = f2bf(w);
}

// ---- prep: W12T[128][128] bf16 = (Wout1@Wout2)^T ; b12 = bout1@Wout2 + bout2 ----
__global__ void prep_w12(const float* __restrict__ Wout1, const float* __restrict__ Wout2,
                         const float* __restrict__ bout1, const float* __restrict__ bout2,
                         unsigned short* __restrict__ W12T, float* __restrict__ b12) {
    int idx = blockIdx.x * 256 + threadIdx.x;       // 16384 = 64 blocks
    int c = idx >> 7, k = idx & 127;
    float s = 0.f;
    for (int j = 0; j < 128; ++j) s += Wout1[k * 128 + j] * Wout2[j * 128 + c];
    W12T[c * 128 + k] = f2bf(s);
    if (k == 0) {
        float t = bout2[c];
        for (int j = 0; j < 128; ++j) t += bout1[j] * Wout2[j * 128 + c];
        b12[c] = t;
    }
}

// ---- G1: fused projection GEMM. q = query+qpos (bf16), [value|off|logits] = q @ Wcat ----
__global__ __launch_bounds__(256) void g1_kernel(
    const float* __restrict__ query, const float* __restrict__ qpos,
    const unsigned short* __restrict__ WcatT,
    const float* __restrict__ bv, const float* __restrict__ boff, const float* __restrict__ battn,
    unsigned short* __restrict__ value_bf, float* __restrict__ off_out, float* __restrict__ logits_out)
{
    __shared__ short Alds[64 * 128];   // bf16, XOR-swizzled rows
    const int tid = threadIdx.x;
    const int rowBase = blockIdx.x * 64;

    {
        int r = tid >> 2;                 // 0..63
        int c0 = (tid & 3) * 32;          // 0,32,64,96
        const float4* qa = (const float4*)(query + (size_t)(rowBase + r) * CC + c0);
        const float4* qb = (const float4*)(qpos  + (size_t)(rowBase + r) * CC + c0);
#pragma unroll
        for (int j = 0; j < 4; ++j) {
            float4 x0 = qa[2 * j], x1 = qa[2 * j + 1];
            float4 y0 = qb[2 * j], y1 = qb[2 * j + 1];
            short8 w;
            w[0] = (short)f2bf(x0.x + y0.x); w[1] = (short)f2bf(x0.y + y0.y);
            w[2] = (short)f2bf(x0.z + y0.z); w[3] = (short)f2bf(x0.w + y0.w);
            w[4] = (short)f2bf(x1.x + y1.x); w[5] = (short)f2bf(x1.y + y1.y);
            w[6] = (short)f2bf(x1.z + y1.z); w[7] = (short)f2bf(x1.w + y1.w);
            int byte = (r * 256 + (c0 + j * 8) * 2) ^ ((r & 7) << 4);
            *(short8*)((char*)Alds + byte) = w;
        }
    }
    __syncthreads();

    const int wave = tid >> 6, lane = tid & 63;
    const int arow = lane & 15, kq = lane >> 4;
    const int wrow = wave * 16;

    f32x4 acc[14];
#pragma unroll
    for (int t = 0; t < 14; ++t) acc[t] = (f32x4){0.f, 0.f, 0.f, 0.f};

#pragma unroll
    for (int ks = 0; ks < 4; ++ks) {
        int r = wrow + arow;
        int byte = (r * 256 + (ks * 32 + kq * 8) * 2) ^ ((r & 7) << 4);
        short8 a = *(const short8*)((const char*)Alds + byte);
#pragma unroll
        for (int t = 0; t < 14; ++t) {
            int col = t * 16 + arow;
            short8 b = *(const short8*)(WcatT + (size_t)col * 128 + ks * 32 + kq * 8);
            acc[t] = __builtin_amdgcn_mfma_f32_16x16x32_bf16(a, b, acc[t], 0, 0, 0);
        }
    }

#pragma unroll
    for (int t = 0; t < 14; ++t) {
        int col = t * 16 + (lane & 15);
#pragma unroll
        for (int rr = 0; rr < 4; ++rr) {
            int row = wrow + kq * 4 + rr;
            size_t grow = (size_t)(rowBase + row);
            float v = acc[t][rr];
            if (col < 128) {
                value_bf[grow * 128 + col] = f2bf(v + bv[col]);
            } else if (col < 192) {
                off_out[grow * 64 + (col - 128)] = v + boff[col - 128];
            } else {
                logits_out[grow * 32 + (col - 192)] = v + battn[col - 192];
            }
        }
    }
}

// ---- sampling: LDS-precomputed corner addresses + validity-folded weights,
//      paired-channel gathers (u32 = 2 bf16), 2 samples per iteration per query ----
// 8 queries/block, 32 lanes per query. Phase 1: lane = (h,p) sample. Phase 2:
// lanes 0-15 handle heads 0/1 samples, lanes 16-31 heads 2/3; each lane owns a
// channel pair (lane&15)*2 within the head.
__global__ __launch_bounds__(256) void sample_kernel(
    const unsigned short* __restrict__ value_bf, const float* __restrict__ off_in,
    const float* __restrict__ logits, unsigned short* __restrict__ sampled)
{
    __shared__ int S[8][32][8];   // a00,a01,a10,a11 (byte offs), wxa,wxb,aw*wya,aw*wyb

    const int tid = threadIdx.x;
    const int qi = tid >> 5;
    const int lane = tid & 31;
    const int r = blockIdx.x * 8 + qi;          // query row, 0..79999
    const int b = (r >= NQ) ? 1 : 0;
    const int n = r - b * NQ;
    const int yq = n / XX, xq = n - yq * XX;

    // ---- phase 1: per-sample setup (lane = hp) ----
    {
        float lg = logits[(size_t)r * 32 + lane];
        float m = lg;
        m = fmaxf(m, __shfl_xor(m, 1));
        m = fmaxf(m, __shfl_xor(m, 2));
        m = fmaxf(m, __shfl_xor(m, 4));
        float e = __expf(lg - m);
        float s = e;
        s += __shfl_xor(s, 1);
        s += __shfl_xor(s, 2);
        s += __shfl_xor(s, 4);
        float aw = e / s;

        // faithful reference quirk: x-coord = yq + off0, y-coord = xq + off1
        float2 o = ((const float2*)(off_in + (size_t)r * 64))[lane];
        float gx = (float)yq + o.x;
        float gy = (float)xq + o.y;
        float fx = floorf(gx), fy = floorf(gy);
        int x0 = (int)fx, y0 = (int)fy;
        float wx1 = gx - fx, wy1 = gy - fy;
        float vx0 = ((unsigned)x0 < XX) ? 1.f : 0.f;
        float vx1 = ((unsigned)(x0 + 1) < XX) ? 1.f : 0.f;
        float vy0 = ((unsigned)y0 < YY) ? 1.f : 0.f;
        float vy1 = ((unsigned)(y0 + 1) < YY) ? 1.f : 0.f;
        int x0c = min(max(x0, 0), XX - 1);
        int x1c = min(max(x0 + 1, 0), XX - 1);
        int y0c = min(max(y0, 0), YY - 1);
        int y1c = min(max(y0 + 1, 0), YY - 1);
        int hb = (lane >> 3) * 64;                 // head byte offset within 256B row
        int rowA = y0c * XX, rowB = y1c * XX;
        int4 addrs;
        addrs.x = (rowA + x0c) * 256 + hb;
        addrs.y = (rowA + x1c) * 256 + hb;
        addrs.z = (rowB + x0c) * 256 + hb;
        addrs.w = (rowB + x1c) * 256 + hb;
        int4 wts;
        wts.x = __float_as_int((1.f - wx1) * vx0);
        wts.y = __float_as_int(wx1 * vx1);
        wts.z = __float_as_int(aw * (1.f - wy1) * vy0);
        wts.w = __float_as_int(aw * wy1 * vy1);
        *(int4*)&S[qi][lane][0] = addrs;
        *(int4*)&S[qi][lane][4] = wts;
    }
    __syncthreads();

    // ---- phase 2: gather + weighted accumulate ----
    const char* vb = (const char*)(value_bf + (size_t)b * NQ * 128);
    const int cb = (lane & 15) * 4;    // channel-pair byte offset within head
    const int g16 = lane >> 4;         // 0 -> heads 0,1 ; 1 -> heads 2,3

    float2 acc[2];
    acc[0] = make_float2(0.f, 0.f);
    acc[1] = make_float2(0.f, 0.f);

#pragma unroll
    for (int i = 0; i < 16; ++i) {
        const int hp = g16 * 16 + i;
        int4 ai = *(const int4*)&S[qi][hp][0];
        int4 wi = *(const int4*)&S[qi][hp][4];
        float wxa = __int_as_float(wi.x);
        float wxb = __int_as_float(wi.y);
        float wya = __int_as_float(wi.z);
        float wyb = __int_as_float(wi.w);

        unsigned int u00 = *(const unsigned int*)(vb + ai.x + cb);
        unsigned int u01 = *(const unsigned int*)(vb + ai.y + cb);
        unsigned int u10 = *(const unsigned int*)(vb + ai.z + cb);
        unsigned int u11 = *(const unsigned int*)(vb + ai.w + cb);

        float f00l = __uint_as_float(u00 << 16), f00h = __uint_as_float(u00 & 0xFFFF0000u);
        float f01l = __uint_as_float(u01 << 16), f01h = __uint_as_float(u01 & 0xFFFF0000u);
        float f10l = __uint_as_float(u10 << 16), f10h = __uint_as_float(u10 & 0xFFFF0000u);
        float f11l = __uint_as_float(u11 << 16), f11h = __uint_as_float(u11 & 0xFFFF0000u);

        float tal = fmaf(wxa, f00l, wxb * f01l);
        float tbl = fmaf(wxa, f10l, wxb * f11l);
        float tah = fmaf(wxa, f00h, wxb * f01h);
        float tbh = fmaf(wxa, f10h, wxb * f11h);

        const int j = i >> 3;   // compile-time after unroll
        acc[j].x = fmaf(wya, tal, acc[j].x);
        acc[j].x = fmaf(wyb, tbl, acc[j].x);
        acc[j].y = fmaf(wya, tah, acc[j].y);
        acc[j].y = fmaf(wyb, tbh, acc[j].y);
    }

    // write: acc[j] -> head h = g16*2 + j, channel pair (lane&15)*2, packed u32
    char* sp = (char*)(sampled + (size_t)r * 128);
#pragma unroll
    for (int j = 0; j < 2; ++j) {
        unsigned int packed = ((unsigned int)f2bf(acc[j].y) << 16) | (unsigned int)f2bf(acc[j].x);
        *(unsigned int*)(sp + (g16 * 2 + j) * 64 + cb) = packed;
    }
}

// ---- G2: out = sampled @ W12 + b12 + query (residual). M=80000, N=128, K=128 ----
__global__ __launch_bounds__(256) void g2_kernel(
    const unsigned short* __restrict__ sampled, const unsigned short* __restrict__ W12T,
    const float* __restrict__ b12, const float* __restrict__ query, float* __restrict__ out)
{
    __shared__ short Alds[64 * 128];
    const int tid = threadIdx.x;
    const int rowBase = blockIdx.x * 64;

    {
        int r = tid >> 2;
        int c0 = (tid & 3) * 32;
        const short8* sp = (const short8*)(sampled + (size_t)(rowBase + r) * 128 + c0);
#pragma unroll
        for (int j = 0; j < 4; ++j) {
            short8 w = sp[j];
            int byte = (r * 256 + (c0 + j * 8) * 2) ^ ((r & 7) << 4);
            *(short8*)((char*)Alds + byte) = w;
        }
    }
    __syncthreads();

    const int wave = tid >> 6, lane = tid & 63;
    const int arow = lane & 15, kq = lane >> 4;
    const int wrow = wave * 16;

    f32x4 acc[8];
#pragma unroll
    for (int t = 0; t < 8; ++t) acc[t] = (f32x4){0.f, 0.f, 0.f, 0.f};

#pragma unroll
    for (int ks = 0; ks < 4; ++ks) {
        int r = wrow + arow;
        int byte = (r * 256 + (ks * 32 + kq * 8) * 2) ^ ((r & 7) << 4);
        short8 a = *(const short8*)((const char*)Alds + byte);
#pragma unroll
        for (int t = 0; t < 8; ++t) {
            int col = t * 16 + arow;
            short8 b = *(const short8*)(W12T + (size_t)col * 128 + ks * 32 + kq * 8);
            acc[t] = __builtin_amdgcn_mfma_f32_16x16x32_bf16(a, b, acc[t], 0, 0, 0);
        }
    }

#pragma unroll
    for (int t = 0; t < 8; ++t) {
        int col = t * 16 + (lane & 15);
#pragma unroll
        for (int rr = 0; rr < 4; ++rr) {
            int row = wrow + kq * 4 + rr;
            size_t grow = (size_t)(rowBase + row);
            out[grow * 128 + col] = acc[t][rr] + b12[col] + query[grow * 128 + col];
        }
    }
}

extern "C" void kernel_launch(void* const* d_in, const int* in_sizes, int n_in,
                              void* d_out, int out_size, void* d_ws, size_t ws_size,
                              hipStream_t stream) {
    const float* query = (const float*)d_in[0];
    const float* qpos  = (const float*)d_in[1];
    const float* Wv    = (const float*)d_in[2];
    const float* bv    = (const float*)d_in[3];
    const float* Woff  = (const float*)d_in[4];
    const float* boff  = (const float*)d_in[5];
    const float* Wattn = (const float*)d_in[6];
    const float* battn = (const float*)d_in[7];
    const float* Wout1 = (const float*)d_in[8];
    const float* bout1 = (const float*)d_in[9];
    const float* Wout2 = (const float*)d_in[10];
    const float* bout2 = (const float*)d_in[11];
    float* out = (float*)d_out;

    char* ws = (char*)d_ws;
    unsigned short* value_bf = (unsigned short*)(ws);                 // 80000*128*2 = 20,480,000
    float*          off_buf  = (float*)(ws + 20480000);               // 80000*64*4  = 20,480,000
    float*          logits   = (float*)(ws + 40960000);               // 80000*32*4  = 10,240,000
    unsigned short* sampled  = (unsigned short*)(ws + 51200000);      // 80000*128*2 = 20,480,000
    unsigned short* WcatT    = (unsigned short*)(ws + 71680000);      // 224*128*2   = 57,344
    unsigned short* W12T     = (unsigned short*)(ws + 71680000 + 57344);  // 128*128*2 = 32,768
    float*          b12      = (float*)(ws + 71680000 + 57344 + 32768);   // 512

    prep_wcat<<<112, 256, 0, stream>>>(Wv, Woff, Wattn, WcatT);
    prep_w12<<<64, 256, 0, stream>>>(Wout1, Wout2, bout1, bout2, W12T, b12);
    g1_kernel<<<MTOT / 64, 256, 0, stream>>>(query, qpos, WcatT, bv, boff, battn,
                                             value_bf, off_buf, logits);
    sample_kernel<<<MTOT / 8, 256, 0, stream>>>(value_bf, off_buf, logits, sampled);
    g2_kernel<<<MTOT / 64, 256, 0, stream>>>(sampled, W12T, b12, query, out);
}

// Round 3
// 127.608 us; speedup vs baseline: 2.8857x; 1.0830x over previous
//
#include <hip/hip_runtime.h>
#include <hip/hip_bf16.h>

// Problem constants (match setup_inputs): B=2, Y=X=200, N=40000, C=128, H=4, P=8, D=32
#define BQ 2
#define YY 200
#define XX 200
#define NQ 40000
#define CC 128
#define MTOT 80000   // BQ*NQ
#define NCOL 224     // 128 (value) + 64 (off) + 32 (attn logits)
#define NTILES 5000  // MTOT/16

typedef __attribute__((ext_vector_type(8))) short short8;
typedef __attribute__((ext_vector_type(4))) float f32x4;

static __device__ __forceinline__ unsigned short f2bf(float f) {
    union { float f; unsigned int u; } v; v.f = f;
    unsigned int r = v.u + 0x7FFF + ((v.u >> 16) & 1);  // round-to-nearest-even
    return (unsigned short)(r >> 16);
}
static __device__ __forceinline__ unsigned short f2bf_hw(float f) {
    __hip_bfloat16 h = __float2bfloat16(f);
    unsigned short s;
    __builtin_memcpy(&s, &h, 2);
    return s;
}

// ---- prep: WcatT[224][128] bf16 = [Wv | Woff | Wattn] transposed ----
__global__ void prep_wcat(const float* __restrict__ Wv, const float* __restrict__ Woff,
                          const float* __restrict__ Wattn, unsigned short* __restrict__ WcatT) {
    int idx = blockIdx.x * 256 + threadIdx.x;       // 224*128 = 28672 = 112 blocks
    if (idx >= NCOL * CC) return;
    int c = idx >> 7, k = idx & 127;
    float w = (c < 128) ? Wv[k * 128 + c]
            : (c < 192) ? Woff[k * 64 + (c - 128)]
                        : Wattn[k * 32 + (c - 192)];
    WcatT[c * 128 + k] = f2bf(w);
}

// ---- prep: W12T[128][128] bf16 = (Wout1@Wout2)^T ; b12 = bout1@Wout2 + bout2 ----
__global__ void prep_w12(const float* __restrict__ Wout1, const float* __restrict__ Wout2,
                         const float* __restrict__ bout1, const float* __restrict__ bout2,
                         unsigned short* __restrict__ W12T, float* __restrict__ b12) {
    int idx = blockIdx.x * 256 + threadIdx.x;       // 16384 = 64 blocks
    int c = idx >> 7, k = idx & 127;
    float s = 0.f;
    for (int j = 0; j < 128; ++j) s += Wout1[k * 128 + j] * Wout2[j * 128 + c];
    W12T[c * 128 + k] = f2bf(s);
    if (k == 0) {
        float t = bout2[c];
        for (int j = 0; j < 128; ++j) t += bout1[j] * Wout2[j * 128 + c];
        b12[c] = t;
    }
}

// ---- G1: fused projection GEMM, barrier-free reg-direct MFMA ----
// Each wave owns a 16-row tile; A loaded f32 from global in fragment layout,
// converted to bf16 in regs; B fragments read from L2 (loop-invariant addrs).
__global__ __launch_bounds__(256) void g1_kernel(
    const float* __restrict__ query, const float* __restrict__ qpos,
    const unsigned short* __restrict__ WcatT,
    const float* __restrict__ bv, const float* __restrict__ boff, const float* __restrict__ battn,
    unsigned short* __restrict__ value_bf, float* __restrict__ off_out, float* __restrict__ logits_out)
{
    const int tid = threadIdx.x;
    const int lane = tid & 63;
    const int arow = lane & 15, kq = lane >> 4;
    const int wid = blockIdx.x * 4 + (tid >> 6);
    const int nw = gridDim.x * 4;

    // per-lane biases for each of the 14 col-tiles (col = t*16 + arow)
    float bias[14];
#pragma unroll
    for (int t = 0; t < 8; ++t) bias[t] = bv[t * 16 + arow];
#pragma unroll
    for (int t = 0; t < 4; ++t) bias[8 + t] = boff[t * 16 + arow];
#pragma unroll
    for (int t = 0; t < 2; ++t) bias[12 + t] = battn[t * 16 + arow];

    const char* Bb = (const char*)WcatT + (arow * 256 + kq * 16);

    for (int tile = wid; tile < NTILES; tile += nw) {
        const float4* pq = (const float4*)(query + (size_t)(tile * 16 + arow) * 128 + kq * 8);
        const float4* pp = (const float4*)(qpos  + (size_t)(tile * 16 + arow) * 128 + kq * 8);

        float4 xa[8], xb[8];
#pragma unroll
        for (int ks = 0; ks < 4; ++ks) {
            xa[2 * ks]     = pq[8 * ks];
            xa[2 * ks + 1] = pq[8 * ks + 1];
            xb[2 * ks]     = pp[8 * ks];
            xb[2 * ks + 1] = pp[8 * ks + 1];
        }

        short8 af[4];
#pragma unroll
        for (int ks = 0; ks < 4; ++ks) {
            const float* u = (const float*)&xa[2 * ks];
            const float* v = (const float*)&xb[2 * ks];
            short8 a;
#pragma unroll
            for (int j = 0; j < 8; ++j) a[j] = (short)f2bf_hw(u[j] + v[j]);
            af[ks] = a;
        }

        f32x4 acc[14];
#pragma unroll
        for (int t = 0; t < 14; ++t) acc[t] = (f32x4){0.f, 0.f, 0.f, 0.f};

#pragma unroll
        for (int ks = 0; ks < 4; ++ks) {
#pragma unroll
            for (int t = 0; t < 14; ++t) {
                short8 b = *(const short8*)(Bb + t * 4096 + ks * 64);
                acc[t] = __builtin_amdgcn_mfma_f32_16x16x32_bf16(af[ks], b, acc[t], 0, 0, 0);
            }
        }

#pragma unroll
        for (int t = 0; t < 14; ++t) {
#pragma unroll
            for (int rr = 0; rr < 4; ++rr) {
                size_t grow = (size_t)(tile * 16 + kq * 4 + rr);
                float vv = acc[t][rr] + bias[t];
                if (t < 8)
                    value_bf[grow * 128 + t * 16 + arow] = f2bf_hw(vv);
                else if (t < 12)
                    off_out[grow * 64 + (t - 8) * 16 + arow] = vv;
                else
                    logits_out[grow * 32 + (t - 12) * 16 + arow] = vv;
            }
        }
    }
}

// ---- sampling: LDS-precomputed corner addresses + validity-folded weights,
//      paired-channel gathers (u32 = 2 bf16), 2 samples per iteration per query ----
__global__ __launch_bounds__(256) void sample_kernel(
    const unsigned short* __restrict__ value_bf, const float* __restrict__ off_in,
    const float* __restrict__ logits, unsigned short* __restrict__ sampled)
{
    __shared__ int S[8][32][8];   // a00,a01,a10,a11 (byte offs), wxa,wxb,aw*wya,aw*wyb

    const int tid = threadIdx.x;
    const int qi = tid >> 5;
    const int lane = tid & 31;
    const int r = blockIdx.x * 8 + qi;          // query row, 0..79999
    const int b = (r >= NQ) ? 1 : 0;
    const int n = r - b * NQ;
    const int yq = n / XX, xq = n - yq * XX;

    // ---- phase 1: per-sample setup (lane = hp) ----
    {
        float lg = logits[(size_t)r * 32 + lane];
        float m = lg;
        m = fmaxf(m, __shfl_xor(m, 1));
        m = fmaxf(m, __shfl_xor(m, 2));
        m = fmaxf(m, __shfl_xor(m, 4));
        float e = __expf(lg - m);
        float s = e;
        s += __shfl_xor(s, 1);
        s += __shfl_xor(s, 2);
        s += __shfl_xor(s, 4);
        float aw = e / s;

        // faithful reference quirk: x-coord = yq + off0, y-coord = xq + off1
        float2 o = ((const float2*)(off_in + (size_t)r * 64))[lane];
        float gx = (float)yq + o.x;
        float gy = (float)xq + o.y;
        float fx = floorf(gx), fy = floorf(gy);
        int x0 = (int)fx, y0 = (int)fy;
        float wx1 = gx - fx, wy1 = gy - fy;
        float vx0 = ((unsigned)x0 < XX) ? 1.f : 0.f;
        float vx1 = ((unsigned)(x0 + 1) < XX) ? 1.f : 0.f;
        float vy0 = ((unsigned)y0 < YY) ? 1.f : 0.f;
        float vy1 = ((unsigned)(y0 + 1) < YY) ? 1.f : 0.f;
        int x0c = min(max(x0, 0), XX - 1);
        int x1c = min(max(x0 + 1, 0), XX - 1);
        int y0c = min(max(y0, 0), YY - 1);
        int y1c = min(max(y0 + 1, 0), YY - 1);
        int hb = (lane >> 3) * 64;                 // head byte offset within 256B row
        int rowA = y0c * XX, rowB = y1c * XX;
        int4 addrs;
        addrs.x = (rowA + x0c) * 256 + hb;
        addrs.y = (rowA + x1c) * 256 + hb;
        addrs.z = (rowB + x0c) * 256 + hb;
        addrs.w = (rowB + x1c) * 256 + hb;
        int4 wts;
        wts.x = __float_as_int((1.f - wx1) * vx0);
        wts.y = __float_as_int(wx1 * vx1);
        wts.z = __float_as_int(aw * (1.f - wy1) * vy0);
        wts.w = __float_as_int(aw * wy1 * vy1);
        *(int4*)&S[qi][lane][0] = addrs;
        *(int4*)&S[qi][lane][4] = wts;
    }
    __syncthreads();

    // ---- phase 2: gather + weighted accumulate ----
    const char* vb = (const char*)(value_bf + (size_t)b * NQ * 128);
    const int cb = (lane & 15) * 4;    // channel-pair byte offset within head
    const int g16 = lane >> 4;         // 0 -> heads 0,1 ; 1 -> heads 2,3

    float2 acc[2];
    acc[0] = make_float2(0.f, 0.f);
    acc[1] = make_float2(0.f, 0.f);

#pragma unroll
    for (int i = 0; i < 16; ++i) {
        const int hp = g16 * 16 + i;
        int4 ai = *(const int4*)&S[qi][hp][0];
        int4 wi = *(const int4*)&S[qi][hp][4];
        float wxa = __int_as_float(wi.x);
        float wxb = __int_as_float(wi.y);
        float wya = __int_as_float(wi.z);
        float wyb = __int_as_float(wi.w);

        unsigned int u00 = *(const unsigned int*)(vb + ai.x + cb);
        unsigned int u01 = *(const unsigned int*)(vb + ai.y + cb);
        unsigned int u10 = *(const unsigned int*)(vb + ai.z + cb);
        unsigned int u11 = *(const unsigned int*)(vb + ai.w + cb);

        float f00l = __uint_as_float(u00 << 16), f00h = __uint_as_float(u00 & 0xFFFF0000u);
        float f01l = __uint_as_float(u01 << 16), f01h = __uint_as_float(u01 & 0xFFFF0000u);
        float f10l = __uint_as_float(u10 << 16), f10h = __uint_as_float(u10 & 0xFFFF0000u);
        float f11l = __uint_as_float(u11 << 16), f11h = __uint_as_float(u11 & 0xFFFF0000u);

        float tal = fmaf(wxa, f00l, wxb * f01l);
        float tbl = fmaf(wxa, f10l, wxb * f11l);
        float tah = fmaf(wxa, f00h, wxb * f01h);
        float tbh = fmaf(wxa, f10h, wxb * f11h);

        const int j = i >> 3;   // compile-time after unroll
        acc[j].x = fmaf(wya, tal, acc[j].x);
        acc[j].x = fmaf(wyb, tbl, acc[j].x);
        acc[j].y = fmaf(wya, tah, acc[j].y);
        acc[j].y = fmaf(wyb, tbh, acc[j].y);
    }

    // write: acc[j] -> head h = g16*2 + j, channel pair (lane&15)*2, packed u32
    char* sp = (char*)(sampled + (size_t)r * 128);
#pragma unroll
    for (int j = 0; j < 2; ++j) {
        unsigned int packed = ((unsigned int)f2bf(acc[j].y) << 16) | (unsigned int)f2bf(acc[j].x);
        *(unsigned int*)(sp + (g16 * 2 + j) * 64 + cb) = packed;
    }
}

// ---- G2: out = sampled @ W12 + b12 + query (residual), barrier-free reg-direct ----
__global__ __launch_bounds__(256) void g2_kernel(
    const unsigned short* __restrict__ sampled, const unsigned short* __restrict__ W12T,
    const float* __restrict__ b12, const float* __restrict__ query, float* __restrict__ out)
{
    const int tid = threadIdx.x;
    const int lane = tid & 63;
    const int arow = lane & 15, kq = lane >> 4;
    const int wid = blockIdx.x * 4 + (tid >> 6);
    const int nw = gridDim.x * 4;

    float bias[8];
#pragma unroll
    for (int t = 0; t < 8; ++t) bias[t] = b12[t * 16 + arow];

    const char* Bb = (const char*)W12T + (arow * 256 + kq * 16);

    for (int tile = wid; tile < NTILES; tile += nw) {
        const char* pa = (const char*)sampled + (size_t)(tile * 16 + arow) * 256 + kq * 16;

        short8 af[4];
#pragma unroll
        for (int ks = 0; ks < 4; ++ks) af[ks] = *(const short8*)(pa + ks * 64);

        f32x4 acc[8];
#pragma unroll
        for (int t = 0; t < 8; ++t) acc[t] = (f32x4){0.f, 0.f, 0.f, 0.f};

#pragma unroll
        for (int ks = 0; ks < 4; ++ks) {
#pragma unroll
            for (int t = 0; t < 8; ++t) {
                short8 b = *(const short8*)(Bb + t * 4096 + ks * 64);
                acc[t] = __builtin_amdgcn_mfma_f32_16x16x32_bf16(af[ks], b, acc[t], 0, 0, 0);
            }
        }

#pragma unroll
        for (int t = 0; t < 8; ++t) {
#pragma unroll
            for (int rr = 0; rr < 4; ++rr) {
                size_t grow = (size_t)(tile * 16 + kq * 4 + rr);
                size_t idx = grow * 128 + t * 16 + arow;
                out[idx] = acc[t][rr] + bias[t] + query[idx];
            }
        }
    }
}

extern "C" void kernel_launch(void* const* d_in, const int* in_sizes, int n_in,
                              void* d_out, int out_size, void* d_ws, size_t ws_size,
                              hipStream_t stream) {
    const float* query = (const float*)d_in[0];
    const float* qpos  = (const float*)d_in[1];
    const float* Wv    = (const float*)d_in[2];
    const float* bv    = (const float*)d_in[3];
    const float* Woff  = (const float*)d_in[4];
    const float* boff  = (const float*)d_in[5];
    const float* Wattn = (const float*)d_in[6];
    const float* battn = (const float*)d_in[7];
    const float* Wout1 = (const float*)d_in[8];
    const float* bout1 = (const float*)d_in[9];
    const float* Wout2 = (const float*)d_in[10];
    const float* bout2 = (const float*)d_in[11];
    float* out = (float*)d_out;

    char* ws = (char*)d_ws;
    unsigned short* value_bf = (unsigned short*)(ws);                 // 80000*128*2 = 20,480,000
    float*          off_buf  = (float*)(ws + 20480000);               // 80000*64*4  = 20,480,000
    float*          logits   = (float*)(ws + 40960000);               // 80000*32*4  = 10,240,000
    unsigned short* sampled  = (unsigned short*)(ws + 51200000);      // 80000*128*2 = 20,480,000
    unsigned short* WcatT    = (unsigned short*)(ws + 71680000);      // 224*128*2   = 57,344
    unsigned short* W12T     = (unsigned short*)(ws + 71680000 + 57344);  // 128*128*2 = 32,768
    float*          b12      = (float*)(ws + 71680000 + 57344 + 32768);   // 512

    prep_wcat<<<112, 256, 0, stream>>>(Wv, Woff, Wattn, WcatT);
    prep_w12<<<64, 256, 0, stream>>>(Wout1, Wout2, bout1, bout2, W12T, b12);
    g1_kernel<<<625, 256, 0, stream>>>(query, qpos, WcatT, bv, boff, battn,
                                       value_bf, off_buf, logits);
    sample_kernel<<<MTOT / 8, 256, 0, stream>>>(value_bf, off_buf, logits, sampled);
    g2_kernel<<<625, 256, 0, stream>>>(sampled, W12T, b12, query, out);
}